// Round 7
// baseline (791.867 us; speedup 1.0000x reference)
//
#include <hip/hip_runtime.h>
#include <cmath>

#define NN 50000
#define CAP 64               // ELL capacity; P(Binomial(800k,1/50k) > 64 anywhere) ~ 1e-16

typedef short v8s __attribute__((ext_vector_type(8)));   // 8 x bf16 (4 VGPRs)
typedef float v4f __attribute__((ext_vector_type(4)));

__device__ __forceinline__ float b2f(unsigned short u) {
    return __uint_as_float(((unsigned int)u) << 16);
}
__device__ __forceinline__ unsigned short f2b(float f) {
    unsigned int x = __float_as_uint(f);
    x += 0x7fffu + ((x >> 16) & 1u);          // round-to-nearest-even
    return (unsigned short)(x >> 16);
}

// async global->LDS, 16B per lane. LDS dest must be wave-contiguous (base + lane*16).
__device__ __forceinline__ void gld16(const void* g, void* l) {
    __builtin_amdgcn_global_load_lds(
        (const __attribute__((address_space(1))) unsigned int*)g,
        (__attribute__((address_space(3))) unsigned int*)l, 16, 0, 0);
}

// ---- dtype sniffer: mode=0 -> inputs are bf16, mode=1 -> inputs are float32 ----
__global__ void sniff_kernel(const unsigned short* __restrict__ x, int* __restrict__ mode) {
    if (threadIdx.x == 0 && blockIdx.x == 0) {
        int c = 0;
        for (int i = 0; i < 128; ++i) {
            unsigned int e = (x[i] >> 7) & 0xFFu;
            if (e >= 100u && e <= 140u) ++c;
        }
        *mode = (c >= 112) ? 0 : 1;
    }
}

// ---- ELL fill: one atomic pass, no scan ----
__global__ void fill_kernel(const int* __restrict__ src, const int* __restrict__ dst,
                            int* __restrict__ cnt, unsigned short* __restrict__ ell, int E) {
    int e = blockIdx.x * blockDim.x + threadIdx.x;
    if (e < E) {
        int d = dst[e];
        int pos = atomicAdd(&cnt[d], 1);
        if (pos < CAP) ell[d * CAP + pos] = (unsigned short)src[e];
    }
}

// ---- dinv from counts ----
__global__ void dinv_kernel(const int* __restrict__ cnt, float* __restrict__ dinv, int n) {
    int i = blockIdx.x * blockDim.x + threadIdx.x;
    if (i < n) {
        int d = cnt[i];
        dinv[i] = (d > 0) ? rsqrtf((float)d) : 0.0f;
    }
}

// ---- fused prep: pack x (->xb, ld128), transpose W1/W2/W3 -> WT bf16, biases ----
__global__ void prep_kernel(const void* __restrict__ x,
                            const void* __restrict__ W1, const void* __restrict__ W2,
                            const void* __restrict__ W3, const void* __restrict__ b1,
                            const void* __restrict__ b2, const void* __restrict__ b3,
                            unsigned short* __restrict__ xb,
                            unsigned short* __restrict__ WT1, unsigned short* __restrict__ WT2,
                            unsigned short* __restrict__ WT3, unsigned short* __restrict__ bb1,
                            unsigned short* __restrict__ bb2, unsigned short* __restrict__ bb3,
                            const int* __restrict__ modep) {
    int mode = *modep;
    int b = blockIdx.x, t = threadIdx.x;
    if (b < 3125) {                                   // pack x: NN*16 uint4 chunks
        int idx = b * 256 + t;
        if (mode == 0) {
            ((uint4*)xb)[idx] = ((const uint4*)x)[idx];
        } else {
            const float* xf = (const float*)x + (size_t)idx * 8;
            unsigned short o[8];
#pragma unroll
            for (int i = 0; i < 8; ++i) o[i] = f2b(xf[i]);
            ((uint4*)xb)[idx] = *(const uint4*)o;
        }
    } else if (b < 3381) {                            // WT1 [256][256] from W1[256][256]
        int idx = (b - 3125) * 256 + t;
        int n = idx >> 8, k = idx & 255;
        WT1[idx] = mode ? f2b(((const float*)W1)[k * 256 + n])
                        : ((const unsigned short*)W1)[k * 256 + n];
    } else if (b < 3893) {                            // WT2 [256][512] from W2[512][256]
        int idx = (b - 3381) * 256 + t;
        int n = idx >> 9, k = idx & 511;
        WT2[idx] = mode ? f2b(((const float*)W2)[k * 256 + n])
                        : ((const unsigned short*)W2)[k * 256 + n];
    } else if (b < 4149) {                            // WT3 [128][512] from W3[512][128]
        int idx = (b - 3893) * 256 + t;
        int n = idx >> 9, k = idx & 511;
        WT3[idx] = mode ? f2b(((const float*)W3)[k * 128 + n])
                        : ((const unsigned short*)W3)[k * 128 + n];
    } else {                                          // biases
        if (t < 256) {
            bb1[t] = mode ? f2b(((const float*)b1)[t]) : ((const unsigned short*)b1)[t];
            bb2[t] = mode ? f2b(((const float*)b2)[t]) : ((const unsigned short*)b2)[t];
        }
        if (t < 128)
            bb3[t] = mode ? f2b(((const float*)b3)[t]) : ((const unsigned short*)b3)[t];
    }
}

// ---- fused ChebConv layer: per block (64 dst rows x N cols):
//  phase 1: gather x1 = -dinv*A*dinv*h for own 64 rows -> LDS (spmm work)
//  phase 2: MFMA K-loop, A = [staged h cols | LDS x1 cols], out = tanh?(A@W + b)
// 3 blocks/CU resident (52KB LDS) -> one block's gather overlaps another's MFMA.
// FPL: h_in width = 64*FPL (2->128, 4->256); NT: N = NT*64 (4->256, 2->128)
template <int FPL, int NT>
__global__ __launch_bounds__(256, 3) void fused_kernel(
    const unsigned short* __restrict__ h_in,          // [NN][KH]
    const int* __restrict__ cnt, const unsigned short* __restrict__ ell,
    const float* __restrict__ dinv,
    const unsigned short* __restrict__ WT,            // [N][K] bf16
    const unsigned short* __restrict__ bias,          // bf16
    void* __restrict__ out, int ldo,
    int dotanh, int is_final, const int* __restrict__ modep) {
    constexpr int KH = 64 * FPL;          // h width
    constexpr int K  = 2 * KH;            // concat width
    constexpr int JH = KH / 32;           // h K-steps
    constexpr int N  = NT * 64;
    __shared__ unsigned short lds[2048 + N * 32 + JH * 2048];
    unsigned short* As = lds;                          // A-stage [64][32]
    unsigned short* Bs = lds + 2048;                   // B-stage [N][32]
    unsigned short* X1 = lds + 2048 + N * 32;          // x1 [JH][64][32]

    const int tid = threadIdx.x;
    const int wave = tid >> 6, lane = tid & 63, quad = lane >> 4, l16 = lane & 15;
    const int m0 = blockIdx.x * 64;

    // ---- phase 1: gather x1 for nodes m0 + wave*16 .. +16 ----
    for (int i = 0; i < 16; ++i) {
        int node = m0 + wave * 16 + i;
        if (node >= NN) break;
        int c = min(cnt[node], CAP);
        int sl = (int)ell[node * CAP + lane];          // coalesced 128B; junk lanes unused
        float dl = dinv[sl];
        float acc[FPL];
#pragma unroll
        for (int f = 0; f < FPL; ++f) acc[f] = 0.f;
        const int col = lane * FPL;
        int g = 0;
        for (; g + 8 <= c; g += 8) {
            int s[8]; float d[8];
#pragma unroll
            for (int q = 0; q < 8; ++q) { s[q] = __shfl(sl, g + q); d[q] = __shfl(dl, g + q); }
            if (FPL == 4) {
                ushort4 v[8];
#pragma unroll
                for (int q = 0; q < 8; ++q)
                    v[q] = *(const ushort4*)(h_in + (size_t)s[q] * KH + col);
#pragma unroll
                for (int q = 0; q < 8; ++q) {
                    acc[0] += d[q] * b2f(v[q].x); acc[1] += d[q] * b2f(v[q].y);
                    acc[2] += d[q] * b2f(v[q].z); acc[3] += d[q] * b2f(v[q].w);
                }
            } else {
                ushort2 v[8];
#pragma unroll
                for (int q = 0; q < 8; ++q)
                    v[q] = *(const ushort2*)(h_in + (size_t)s[q] * KH + col);
#pragma unroll
                for (int q = 0; q < 8; ++q) {
                    acc[0] += d[q] * b2f(v[q].x); acc[1] += d[q] * b2f(v[q].y);
                }
            }
        }
        for (; g < c; ++g) {
            int sg = __shfl(sl, g);
            float dg = __shfl(dl, g);
            const unsigned short* hp = h_in + (size_t)sg * KH + col;
            if (FPL == 4) {
                ushort4 v = *(const ushort4*)hp;
                acc[0] += dg * b2f(v.x); acc[1] += dg * b2f(v.y);
                acc[2] += dg * b2f(v.z); acc[3] += dg * b2f(v.w);
            } else {
                ushort2 v = *(const ushort2*)hp;
                acc[0] += dg * b2f(v.x); acc[1] += dg * b2f(v.y);
            }
        }
        float dn = -dinv[node];
        int row = node - m0;
        if (FPL == 4) {
            unsigned short o[4];
#pragma unroll
            for (int q = 0; q < 4; ++q) o[q] = f2b(acc[q] * dn);
            *(ushort4*)&X1[(lane >> 3) * 2048 + row * 32 + (lane & 7) * 4] = *(const ushort4*)o;
        } else {
            unsigned short o[2];
            o[0] = f2b(acc[0] * dn); o[1] = f2b(acc[1] * dn);
            *(ushort2*)&X1[(lane >> 4) * 2048 + row * 32 + (lane & 15) * 2] = *(const ushort2*)o;
        }
    }
    __syncthreads();

    // ---- phase 2: MFMA K-loop ----
    v4f acc2[4][NT];
#pragma unroll
    for (int mi = 0; mi < 4; ++mi)
#pragma unroll
        for (int ni = 0; ni < NT; ++ni) acc2[mi][ni] = (v4f){0.f, 0.f, 0.f, 0.f};

    int arow = m0 + (tid >> 2);
    if (arow >= NN) arow = NN - 1;
    const unsigned short* gpa = h_in + (size_t)arow * KH + (tid & 3) * 8;
    const unsigned short* gpb[NT];
#pragma unroll
    for (int r = 0; r < NT; ++r) {
        int cb = tid + r * 256;
        gpb[r] = WT + (size_t)(cb >> 2) * K + (cb & 3) * 8;
    }

    for (int j = 0; j < K / 32; ++j) {
        int k0 = j * 32;
        if (j < JH) gld16(gpa + k0, &As[tid * 8]);
#pragma unroll
        for (int r = 0; r < NT; ++r) gld16(gpb[r] + k0, &Bs[(tid + r * 256) * 8]);
        __syncthreads();

        const unsigned short* aSrc = (j < JH) ? As : (X1 + (j - JH) * 2048);
        v8s a_frag[4], b_frag[NT];
#pragma unroll
        for (int mi = 0; mi < 4; ++mi)
            a_frag[mi] = *(const v8s*)&aSrc[(mi * 16 + l16) * 32 + quad * 8];
#pragma unroll
        for (int ni = 0; ni < NT; ++ni)
            b_frag[ni] = *(const v8s*)&Bs[(wave * NT * 16 + ni * 16 + l16) * 32 + quad * 8];
#pragma unroll
        for (int mi = 0; mi < 4; ++mi)
#pragma unroll
            for (int ni = 0; ni < NT; ++ni)
                acc2[mi][ni] = __builtin_amdgcn_mfma_f32_16x16x32_bf16(a_frag[mi], b_frag[ni],
                                                                       acc2[mi][ni], 0, 0, 0);
        __syncthreads();
    }

    int fin = is_final ? *modep : 0;
#pragma unroll
    for (int ni = 0; ni < NT; ++ni) {
        int colc = wave * NT * 16 + ni * 16 + l16;
        float bv = b2f(bias[colc]);
#pragma unroll
        for (int mi = 0; mi < 4; ++mi) {
#pragma unroll
            for (int r = 0; r < 4; ++r) {
                int row = m0 + mi * 16 + quad * 4 + r;
                if (row < NN) {
                    float v = acc2[mi][ni][r] + bv;
                    if (dotanh) v = tanhf(v);
                    if (fin) ((float*)out)[(size_t)row * ldo + colc] = v;
                    else     ((unsigned short*)out)[(size_t)row * ldo + colc] = f2b(v);
                }
            }
        }
    }
}

static inline size_t al256(size_t x) { return (x + 255) & ~(size_t)255; }

extern "C" void kernel_launch(void* const* d_in, const int* in_sizes, int n_in,
                              void* d_out, int out_size, void* d_ws, size_t ws_size,
                              hipStream_t stream) {
    const void* x  = d_in[0];
    const int* src = (const int*)d_in[1];
    const int* dst = (const int*)d_in[2];
    const void* W1 = d_in[3]; const void* b1 = d_in[4];
    const void* W2 = d_in[5]; const void* b2 = d_in[6];
    const void* W3 = d_in[7]; const void* b3 = d_in[8];
    const int E = in_sizes[1];

    // workspace carve-up (~58.5 MB)
    char* p = (char*)d_ws;
    int* mode     = (int*)p;            p += 256;
    int* cnt      = (int*)p;            p += al256((size_t)NN * 4);
    float* dinv   = (float*)p;          p += al256((size_t)NN * 4);
    unsigned short* ell = (unsigned short*)p; p += al256((size_t)NN * CAP * 2);
    unsigned short* WT1 = (unsigned short*)p; p += al256((size_t)256 * 256 * 2);
    unsigned short* WT2 = (unsigned short*)p; p += al256((size_t)256 * 512 * 2);
    unsigned short* WT3 = (unsigned short*)p; p += al256((size_t)128 * 512 * 2);
    unsigned short* bb1 = (unsigned short*)p; p += al256((size_t)256 * 2);
    unsigned short* bb2 = (unsigned short*)p; p += al256((size_t)256 * 2);
    unsigned short* bb3 = (unsigned short*)p; p += al256((size_t)128 * 2);
    unsigned short* bufA = (unsigned short*)p; p += al256((size_t)NN * 256 * 2);
    unsigned short* bufB = (unsigned short*)p; p += al256((size_t)NN * 256 * 2);
    unsigned short* xb = bufB;             // x packed (ld 128) aliases bufB head; dead after L1

    hipMemsetAsync(cnt, 0, (size_t)NN * 4, stream);
    sniff_kernel<<<1, 64, 0, stream>>>((const unsigned short*)x, mode);
    prep_kernel<<<4150, 256, 0, stream>>>(x, W1, W2, W3, b1, b2, b3,
                                          xb, WT1, WT2, WT3, bb1, bb2, bb3, mode);
    int eb = (E + 255) / 256;
    fill_kernel<<<eb, 256, 0, stream>>>(src, dst, cnt, ell, E);
    dinv_kernel<<<(NN + 255) / 256, 256, 0, stream>>>(cnt, dinv, NN);

    const int FB = (NN + 63) / 64;         // 782 blocks, 64 rows each

    // L1: h=x (128 cols) -> bufA (256 cols)
    fused_kernel<2, 4><<<FB, 256, 0, stream>>>(xb, cnt, ell, dinv, WT1, bb1,
                                               bufA, 256, 1, 0, mode);
    // L2..L4: ping-pong
    fused_kernel<4, 4><<<FB, 256, 0, stream>>>(bufA, cnt, ell, dinv, WT2, bb2,
                                               bufB, 256, 1, 0, mode);
    fused_kernel<4, 4><<<FB, 256, 0, stream>>>(bufB, cnt, ell, dinv, WT2, bb2,
                                               bufA, 256, 1, 0, mode);
    fused_kernel<4, 4><<<FB, 256, 0, stream>>>(bufA, cnt, ell, dinv, WT2, bb2,
                                               bufB, 256, 1, 0, mode);
    // L5: no tanh -> d_out (50000 x 128, bf16 or fp32 per mode)
    fused_kernel<4, 2><<<FB, 256, 0, stream>>>(bufB, cnt, ell, dinv, WT3, bb3,
                                               d_out, 128, 0, 1, mode);
}

// Round 8
// 555.555 us; speedup vs baseline: 1.4254x; 1.4254x over previous
//
#include <hip/hip_runtime.h>
#include <cmath>

#define NN 50000
#define CAP 64               // ELL capacity; P(deg > 64 anywhere) ~ 1e-16 for E=800k

typedef short v8s __attribute__((ext_vector_type(8)));   // 8 x bf16 (4 VGPRs)
typedef float v4f __attribute__((ext_vector_type(4)));

__device__ __forceinline__ float b2f(unsigned short u) {
    return __uint_as_float(((unsigned int)u) << 16);
}
__device__ __forceinline__ unsigned short f2b(float f) {
    unsigned int x = __float_as_uint(f);
    x += 0x7fffu + ((x >> 16) & 1u);          // round-to-nearest-even
    return (unsigned short)(x >> 16);
}

// async global->LDS, 16B per lane. LDS dest must be wave-contiguous (base + lane*16).
__device__ __forceinline__ void gld16(const void* g, void* l) {
    __builtin_amdgcn_global_load_lds(
        (const __attribute__((address_space(1))) unsigned int*)g,
        (__attribute__((address_space(3))) unsigned int*)l, 16, 0, 0);
}

// ---- dtype sniffer: mode=0 -> inputs are bf16, mode=1 -> inputs are float32 ----
__global__ void sniff_kernel(const unsigned short* __restrict__ x, int* __restrict__ mode) {
    if (threadIdx.x == 0 && blockIdx.x == 0) {
        int c = 0;
        for (int i = 0; i < 128; ++i) {
            unsigned int e = (x[i] >> 7) & 0xFFu;
            if (e >= 100u && e <= 140u) ++c;
        }
        *mode = (c >= 112) ? 0 : 1;
    }
}

// ---- ELL fill: one atomic pass, no scan ----
__global__ void fill_kernel(const int* __restrict__ src, const int* __restrict__ dst,
                            int* __restrict__ cnt, unsigned short* __restrict__ ell, int E) {
    int e = blockIdx.x * blockDim.x + threadIdx.x;
    if (e < E) {
        int d = dst[e];
        int pos = atomicAdd(&cnt[d], 1);
        if (pos < CAP) ell[d * CAP + pos] = (unsigned short)src[e];
    }
}

// ---- dinv from counts ----
__global__ void dinv_kernel(const int* __restrict__ cnt, float* __restrict__ dinv, int n) {
    int i = blockIdx.x * blockDim.x + threadIdx.x;
    if (i < n) {
        int d = cnt[i];
        dinv[i] = (d > 0) ? rsqrtf((float)d) : 0.0f;
    }
}

// ---- fused prep: pack x into buf cols 0:128 (ld 512), W->WT bf16, biases ----
__global__ void prep_kernel(const void* __restrict__ x,
                            const void* __restrict__ W1, const void* __restrict__ W2,
                            const void* __restrict__ W3, const void* __restrict__ b1,
                            const void* __restrict__ b2, const void* __restrict__ b3,
                            unsigned short* __restrict__ buf,
                            unsigned short* __restrict__ WT1, unsigned short* __restrict__ WT2,
                            unsigned short* __restrict__ WT3, unsigned short* __restrict__ bb1,
                            unsigned short* __restrict__ bb2, unsigned short* __restrict__ bb3,
                            const int* __restrict__ modep) {
    int mode = *modep;
    int b = blockIdx.x, t = threadIdx.x;
    if (b < 3125) {                                   // pack x: NN*16 uint4 chunks
        int idx = b * 256 + t;                        // idx < 800000
        int n = idx >> 4, c = idx & 15;
        if (mode == 0) {
            ((uint4*)buf)[n * 64 + c] = ((const uint4*)x)[idx];
        } else {
            const float* xf = (const float*)x + (size_t)idx * 8;
            unsigned short o[8];
#pragma unroll
            for (int i = 0; i < 8; ++i) o[i] = f2b(xf[i]);
            ((uint4*)buf)[n * 64 + c] = *(const uint4*)o;
        }
    } else if (b < 3381) {                            // WT1 [256][256] from W1[256][256]
        int idx = (b - 3125) * 256 + t;
        int n = idx >> 8, k = idx & 255;
        WT1[idx] = mode ? f2b(((const float*)W1)[k * 256 + n])
                        : ((const unsigned short*)W1)[k * 256 + n];
    } else if (b < 3893) {                            // WT2 [256][512] from W2[512][256]
        int idx = (b - 3381) * 256 + t;
        int n = idx >> 9, k = idx & 511;
        WT2[idx] = mode ? f2b(((const float*)W2)[k * 256 + n])
                        : ((const unsigned short*)W2)[k * 256 + n];
    } else if (b < 4149) {                            // WT3 [128][512] from W3[512][128]
        int idx = (b - 3893) * 256 + t;
        int n = idx >> 9, k = idx & 511;
        WT3[idx] = mode ? f2b(((const float*)W3)[k * 128 + n])
                        : ((const unsigned short*)W3)[k * 128 + n];
    } else {                                          // biases
        if (t < 256) {
            bb1[t] = mode ? f2b(((const float*)b1)[t]) : ((const unsigned short*)b1)[t];
            bb2[t] = mode ? f2b(((const float*)b2)[t]) : ((const unsigned short*)b2)[t];
        }
        if (t < 128)
            bb3[t] = mode ? f2b(((const float*)b3)[t]) : ((const unsigned short*)b3)[t];
    }
}

// ---- SpMM (ELL): one wave per dst node; x1[n] = -dinv[n] * sum_e dinv[src]*h[src]
// Wave loads its <=64 ELL entries once (coalesced 128B) + one dinv gather, then
// broadcasts via shfl and issues 8 independent row-gathers per batch.
template <int FPL>   // features per lane: F = 64*FPL (2 -> 128, 4 -> 256)
__global__ void spmm_kernel(const unsigned short* __restrict__ h, int ldh,
                            const int* __restrict__ cnt, const unsigned short* __restrict__ ell,
                            const float* __restrict__ dinv,
                            unsigned short* __restrict__ out, int ldo) {
    int node = blockIdx.x * 4 + (threadIdx.x >> 6);
    int lane = threadIdx.x & 63;
    int c = cnt[node]; c = (c < CAP) ? c : CAP;
    int sl = (int)ell[node * CAP + lane];      // coalesced; lanes >= c hold junk (unused)
    float dl = dinv[sl];
    float acc[FPL];
#pragma unroll
    for (int i = 0; i < FPL; ++i) acc[i] = 0.f;
    const int col = lane * FPL;

    int g = 0;
    for (; g + 8 <= c; g += 8) {
        int s[8]; float d[8];
#pragma unroll
        for (int i = 0; i < 8; ++i) { s[i] = __shfl(sl, g + i); d[i] = __shfl(dl, g + i); }
        if (FPL == 4) {
            ushort4 v[8];
#pragma unroll
            for (int i = 0; i < 8; ++i)
                v[i] = *(const ushort4*)(h + (size_t)s[i] * ldh + col);
#pragma unroll
            for (int i = 0; i < 8; ++i) {
                acc[0] += d[i] * b2f(v[i].x); acc[1] += d[i] * b2f(v[i].y);
                acc[2] += d[i] * b2f(v[i].z); acc[3] += d[i] * b2f(v[i].w);
            }
        } else {
            ushort2 v[8];
#pragma unroll
            for (int i = 0; i < 8; ++i)
                v[i] = *(const ushort2*)(h + (size_t)s[i] * ldh + col);
#pragma unroll
            for (int i = 0; i < 8; ++i) {
                acc[0] += d[i] * b2f(v[i].x); acc[1] += d[i] * b2f(v[i].y);
            }
        }
    }
    for (; g < c; ++g) {
        int sg = __shfl(sl, g);
        float dg = __shfl(dl, g);
        const unsigned short* hp = h + (size_t)sg * ldh + col;
        if (FPL == 4) {
            ushort4 v = *(const ushort4*)hp;
            acc[0] += dg * b2f(v.x); acc[1] += dg * b2f(v.y);
            acc[2] += dg * b2f(v.z); acc[3] += dg * b2f(v.w);
        } else {
            ushort2 v = *(const ushort2*)hp;
            acc[0] += dg * b2f(v.x); acc[1] += dg * b2f(v.y);
        }
    }

    float dn = -dinv[node];
    unsigned short* op = out + (size_t)node * ldo + col;
    if (FPL == 4) {
        ushort4 o;
        o.x = f2b(acc[0] * dn); o.y = f2b(acc[1] * dn);
        o.z = f2b(acc[2] * dn); o.w = f2b(acc[3] * dn);
        *(ushort4*)op = o;
    } else {
        ushort2 o;
        o.x = f2b(acc[0] * dn); o.y = f2b(acc[1] * dn);
        *(ushort2*)op = o;
    }
}

// ---- LDS-staged MFMA GEMM, 128(M) x NQ*64(N) block tile, 2*NQ waves ----
// Wave w: rows (w/NQ)*64..+64, cols (w%NQ)*64..+64; 4x4 mfma tiles, acc 64 VGPR.
// Block covers full output width -> owns its rows -> in-place safe (all K-loop
// A reads complete before epilogue stores).
template <int K32, int NQ>
__global__ void gemm_lds_kernel(const unsigned short* __restrict__ A, int lda,
                                const unsigned short* __restrict__ WT,   // [NQ*64 x K] bf16
                                const unsigned short* __restrict__ bias, // bf16
                                void* __restrict__ out, int ldo,
                                int M, int dotanh, int is_final, const int* __restrict__ modep) {
    constexpr int K    = K32 * 32;
    constexpr int NB   = NQ * 64;
    constexpr int NTHR = 2 * NQ * 64;
    constexpr int ACH  = 128 * 4;                     // 16B chunks of A tile
    constexpr int BCH  = NB * 4;
    constexpr int ROUNDS = (ACH + BCH) / NTHR;
    __shared__ unsigned short lds[(128 + NB) * 32];   // A[128][32] then B[NB][32]

    const int tid = threadIdx.x;
    const int wave = tid >> 6, lane = tid & 63, quad = lane >> 4, l16 = lane & 15;
    const int mh = wave / NQ, nq = wave % NQ;
    const int m0 = blockIdx.x * 128;

    v4f acc[4][4];
#pragma unroll
    for (int mi = 0; mi < 4; ++mi)
#pragma unroll
        for (int ni = 0; ni < 4; ++ni) acc[mi][ni] = (v4f){0.f, 0.f, 0.f, 0.f};

    const unsigned short* gp[ROUNDS];
#pragma unroll
    for (int r = 0; r < ROUNDS; ++r) {
        int c = tid + r * NTHR;
        if (c < ACH) {
            int row = m0 + (c >> 2);
            if (row >= M) row = M - 1;
            gp[r] = A + (size_t)row * lda + (c & 3) * 8;
        } else {
            int cb = c - ACH;
            gp[r] = WT + (size_t)(cb >> 2) * K + (cb & 3) * 8;
        }
    }

    const unsigned short* aT = lds;
    const unsigned short* bT = lds + 128 * 32;

    for (int k0 = 0; k0 < K; k0 += 32) {
#pragma unroll
        for (int r = 0; r < ROUNDS; ++r) {
            int c = tid + r * NTHR;
            gld16(gp[r] + k0, (void*)&lds[c * 8]);
        }
        __syncthreads();

        v8s a_frag[4], b_frag[4];
#pragma unroll
        for (int mi = 0; mi < 4; ++mi)
            a_frag[mi] = *(const v8s*)&aT[(mh * 64 + mi * 16 + l16) * 32 + quad * 8];
#pragma unroll
        for (int ni = 0; ni < 4; ++ni)
            b_frag[ni] = *(const v8s*)&bT[(nq * 64 + ni * 16 + l16) * 32 + quad * 8];
#pragma unroll
        for (int mi = 0; mi < 4; ++mi)
#pragma unroll
            for (int ni = 0; ni < 4; ++ni)
                acc[mi][ni] = __builtin_amdgcn_mfma_f32_16x16x32_bf16(a_frag[mi], b_frag[ni],
                                                                      acc[mi][ni], 0, 0, 0);
        __syncthreads();
    }

    int fin = is_final ? *modep : 0;
#pragma unroll
    for (int ni = 0; ni < 4; ++ni) {
        int colc = nq * 64 + ni * 16 + l16;
        float bv = b2f(bias[colc]);
#pragma unroll
        for (int mi = 0; mi < 4; ++mi) {
#pragma unroll
            for (int r = 0; r < 4; ++r) {
                int row = m0 + mh * 64 + mi * 16 + quad * 4 + r;
                if (row < M) {
                    float v = acc[mi][ni][r] + bv;
                    if (dotanh) v = tanhf(v);
                    if (fin) ((float*)out)[(size_t)row * ldo + colc] = v;
                    else     ((unsigned short*)out)[(size_t)row * ldo + colc] = f2b(v);
                }
            }
        }
    }
}

static inline size_t al256(size_t x) { return (x + 255) & ~(size_t)255; }

extern "C" void kernel_launch(void* const* d_in, const int* in_sizes, int n_in,
                              void* d_out, int out_size, void* d_ws, size_t ws_size,
                              hipStream_t stream) {
    const void* x  = d_in[0];
    const int* src = (const int*)d_in[1];
    const int* dst = (const int*)d_in[2];
    const void* W1 = d_in[3]; const void* b1 = d_in[4];
    const void* W2 = d_in[5]; const void* b2 = d_in[6];
    const void* W3 = d_in[7]; const void* b3 = d_in[8];
    const int E = in_sizes[1];

    // workspace carve-up (~58.6 MB)
    char* p = (char*)d_ws;
    int* mode     = (int*)p;            p += 256;
    int* cnt      = (int*)p;            p += al256((size_t)NN * 4);
    float* dinv   = (float*)p;          p += al256((size_t)NN * 4);
    unsigned short* ell = (unsigned short*)p; p += al256((size_t)NN * CAP * 2);
    unsigned short* WT1 = (unsigned short*)p; p += al256((size_t)256 * 256 * 2);
    unsigned short* WT2 = (unsigned short*)p; p += al256((size_t)256 * 512 * 2);
    unsigned short* WT3 = (unsigned short*)p; p += al256((size_t)128 * 512 * 2);
    unsigned short* bb1 = (unsigned short*)p; p += al256((size_t)256 * 2);
    unsigned short* bb2 = (unsigned short*)p; p += al256((size_t)256 * 2);
    unsigned short* bb3 = (unsigned short*)p; p += al256((size_t)128 * 2);
    unsigned short* buf = (unsigned short*)p; p += al256((size_t)NN * 512 * 2);

    hipMemsetAsync(cnt, 0, (size_t)NN * 4, stream);
    sniff_kernel<<<1, 64, 0, stream>>>((const unsigned short*)x, mode);
    prep_kernel<<<4150, 256, 0, stream>>>(x, W1, W2, W3, b1, b2, b3,
                                          buf, WT1, WT2, WT3, bb1, bb2, bb3, mode);
    int eb = (E + 255) / 256;
    fill_kernel<<<eb, 256, 0, stream>>>(src, dst, cnt, ell, E);
    dinv_kernel<<<(NN + 255) / 256, 256, 0, stream>>>(cnt, dinv, NN);

    const int SPMM_GRID = NN / 4;          // 4 waves (nodes) per 256-thread block
    const int GB = (NN + 127) / 128;       // 391 gemm row-blocks

    // L1: buf = [x(0:128) | x1(128:256)]; gemm K=256 in-place -> cols 0:256
    spmm_kernel<2><<<SPMM_GRID, 256, 0, stream>>>(buf, 512, cnt, ell, dinv, buf + 128, 512);
    gemm_lds_kernel<8, 4><<<GB, 512, 0, stream>>>(buf, 512, WT1, bb1, buf, 512, NN, 1, 0, mode);
    // L2..L4: x1 into cols 256:512, gemm K=512 in-place -> cols 0:256
    spmm_kernel<4><<<SPMM_GRID, 256, 0, stream>>>(buf, 512, cnt, ell, dinv, buf + 256, 512);
    gemm_lds_kernel<16, 4><<<GB, 512, 0, stream>>>(buf, 512, WT2, bb2, buf, 512, NN, 1, 0, mode);
    spmm_kernel<4><<<SPMM_GRID, 256, 0, stream>>>(buf, 512, cnt, ell, dinv, buf + 256, 512);
    gemm_lds_kernel<16, 4><<<GB, 512, 0, stream>>>(buf, 512, WT2, bb2, buf, 512, NN, 1, 0, mode);
    spmm_kernel<4><<<SPMM_GRID, 256, 0, stream>>>(buf, 512, cnt, ell, dinv, buf + 256, 512);
    gemm_lds_kernel<16, 4><<<GB, 512, 0, stream>>>(buf, 512, WT2, bb2, buf, 512, NN, 1, 0, mode);
    // L5 (no tanh) -> d_out (50000 x 128, bf16 or fp32 per mode)
    spmm_kernel<4><<<SPMM_GRID, 256, 0, stream>>>(buf, 512, cnt, ell, dinv, buf + 256, 512);
    gemm_lds_kernel<16, 2><<<GB, 256, 0, stream>>>(buf, 512, WT3, bb3, d_out, 128, NN, 0, 1, mode);
}